// Round 13
// baseline (46.994 us; speedup 1.0000x reference)
//
#include <hip/hip_runtime.h>
#include <math.h>

#define NC     1000
#define NBLK   2000     // 2 column-half blocks per class
#define DIM    2048
#define HALF   1024
#define NBATCH 8192
#define NSLOT  8
#define PERSLOT 250     // 2000 / 8
#define FXSH   44       // count field at bits [44,64)
#define FXMASK ((1ULL << FXSH) - 1)

typedef float f32x4 __attribute__((ext_vector_type(4)));
typedef int   i32x4 __attribute__((ext_vector_type(4)));

// ws: u64 slots[8] + u64 final  (72 bytes, zeroed by memsetAsync each call).
// Loss finalize is fence-free: each block does ONE u64 atomicAdd of
// (1<<44 | fixed_point_lsum); the RETURN VALUE carries both the running sum
// and how many blocks preceded -> the 250th adder per slot forwards the slot
// total to `final`; the 8th slot-finisher computes sqrt and writes out[0].
// Atomicity makes ordering irrelevant (no threadfence -- R6's 92us lesson).

__global__ __launch_bounds__(256) void k_main(
        const int*   __restrict__ y,
        const float* __restrict__ feat,
        const float* __restrict__ centers,
        float* __restrict__ grad_out,             // d_out + 1 (4B-aligned only)
        unsigned long long* __restrict__ slots,   // [8]
        unsigned long long* __restrict__ finals,  // [1]
        float* __restrict__ out) {
    const int c = blockIdx.x >> 1;
    const int h = blockIdx.x & 1;
    const int t = threadIdx.x;
    const int col = h * HALF + t * 4;

    const f32x4 cen = *(const f32x4*)(centers + (size_t)c * DIM + col);

    __shared__ unsigned short sidx[NBATCH];   // 16 KB worst case
    __shared__ int scur;
    if (t == 0) scur = 0;
    __syncthreads();

    // vectorized scan of y: 8192 ints as 2048 int4, 8 per thread
    const i32x4* y4 = (const i32x4*)y;
    for (int j = t; j < NBATCH / 4; j += 256) {
        i32x4 v = y4[j];
        int base = 4 * j;
        if (v.x == c) sidx[atomicAdd(&scur, 1)] = (unsigned short)(base + 0);
        if (v.y == c) sidx[atomicAdd(&scur, 1)] = (unsigned short)(base + 1);
        if (v.z == c) sidx[atomicAdd(&scur, 1)] = (unsigned short)(base + 2);
        if (v.w == c) sidx[atomicAdd(&scur, 1)] = (unsigned short)(base + 3);
    }
    __syncthreads();
    const int n = scur;

    f32x4 acc = (f32x4)(0.f);
    float lsum = 0.f;

    int r = 0;
    for (; r + 4 <= n; r += 4) {
        int i0 = sidx[r], i1 = sidx[r+1], i2 = sidx[r+2], i3 = sidx[r+3];
        f32x4 v0 = *(const f32x4*)(feat + (size_t)i0 * DIM + col);
        f32x4 v1 = *(const f32x4*)(feat + (size_t)i1 * DIM + col);
        f32x4 v2 = *(const f32x4*)(feat + (size_t)i2 * DIM + col);
        f32x4 v3 = *(const f32x4*)(feat + (size_t)i3 * DIM + col);
        acc += v0 + v1 + v2 + v3;
        f32x4 d0 = v0 - cen, d1 = v1 - cen, d2 = v2 - cen, d3 = v3 - cen;
        f32x4 sq = d0 * d0 + d1 * d1 + d2 * d2 + d3 * d3;
        lsum += sq.x + sq.y + sq.z + sq.w;
    }
    for (; r < n; ++r) {
        int i0 = sidx[r];
        f32x4 v0 = *(const f32x4*)(feat + (size_t)i0 * DIM + col);
        acc += v0;
        f32x4 d0 = v0 - cen;
        f32x4 sq = d0 * d0;
        lsum += sq.x + sq.y + sq.z + sq.w;
    }

    // grad = coeff * (centers - mean); coeff = n/(1+n); zero when n == 0
    f32x4 g = (f32x4)(0.f);
    if (n > 0) {
        float fn = (float)n;
        float inv = 1.0f / fn;
        float coeff = fn / (1.0f + fn);
        g = coeff * (cen - acc * inv);
    }
    float* go = grad_out + (size_t)c * DIM + col;   // odd base -> scalar stores
    go[0] = g.x; go[1] = g.y; go[2] = g.z; go[3] = g.w;

    // block-reduce lsum (4 waves)
    for (int sh = 32; sh > 0; sh >>= 1) lsum += __shfl_down(lsum, sh);
    __shared__ float red[4];
    if ((t & 63) == 0) red[t >> 6] = lsum;
    __syncthreads();

    if (t == 0) {
        float bl = red[0] + red[1] + red[2] + red[3];
        // fixed-point (scale 2^16); bl <= ~1e5 -> fits easily in 44 bits
        unsigned long long fx = (unsigned long long)(bl * 65536.0f + 0.5f);
        unsigned long long val = (1ULL << FXSH) | fx;
        unsigned long long old = atomicAdd(&slots[blockIdx.x & (NSLOT - 1)], val);
        if ((old >> FXSH) == PERSLOT - 1) {
            // this add completed the slot: slot total is exact
            unsigned long long slotTot = (old + val) & FXMASK;
            unsigned long long val2 = (1ULL << FXSH) | slotTot;
            unsigned long long old2 = atomicAdd(finals, val2);
            if ((old2 >> FXSH) == NSLOT - 1) {
                double tot = (double)((old2 + val2) & FXMASK) * (1.0 / 65536.0);
                out[0] = (float)(0.5 * sqrt(tot) / (double)NBATCH);
            }
        }
    }
}

extern "C" void kernel_launch(void* const* d_in, const int* in_sizes, int n_in,
                              void* d_out, int out_size, void* d_ws, size_t ws_size,
                              hipStream_t stream) {
    const int*   y       = (const int*)d_in[0];
    const float* feat    = (const float*)d_in[1];
    const float* centers = (const float*)d_in[2];
    float* out = (float*)d_out;

    unsigned long long* slots  = (unsigned long long*)d_ws;
    unsigned long long* finals = slots + NSLOT;

    hipMemsetAsync(d_ws, 0, (NSLOT + 1) * sizeof(unsigned long long), stream);
    k_main<<<NBLK, 256, 0, stream>>>(y, feat, centers, out + 1, slots, finals, out);
}